// Round 2
// baseline (183.123 us; speedup 1.0000x reference)
//
#include <hip/hip_runtime.h>

// MCLLoss: masked L1 loss over 5 overlapping value-ranges of real_img.
// Ranges: (-1,1), (-1,-.5), (-.5,0), (0,.5), (.5,1) — inclusive bounds,
// masks overlap; class_mask takes the LAST matching range index.
// Output layout: [loss, losses[5], class_mask_rescaled[N]]; rescale = cls*0.5-1.
//
// R7 = R6 with the nontemporal-store compile fix (native ext_vector_type(2)
// instead of HIP float2 class — the builtin requires a native vector type).
//
// R6 rationale: R5 (8192 blocks, 2 float4/thread) was 75% issue-idle:
// per-block reduction tail (60 bpermutes + barrier + atomics) amortized over
// only 8KB, 128-deep atomic chains per bank line, and lockstep load bursts.
// Now: 2048 blocks x 8 float4-pairs/thread, counts kept as floats (exact:
// integer values < 2^24) so one 10-float reduction, 256 atomic banks
// (depth 8), nontemporal mask stores so the write stream doesn't evict the
// L3-resident inputs.

#define N_BANKS 256
#define BANK_F  16   // floats per bank (64B line): sums [0..4], counts-as-float [5..9]
#define TPB     256
#define GROUPS  8                 // float4 pairs per thread
#define SPAN    (TPB * GROUPS)    // 2048 float4 per block

typedef float nfloat2 __attribute__((ext_vector_type(2)));  // native vec for nontemporal builtin

__device__ __forceinline__ void proc_elem(float pv, float rv,
                                          float s[5], float c[5], float& ov)
{
    float d = fabsf(pv - rv);
    bool geM1  = rv >= -1.0f;
    bool leM05 = rv <= -0.5f;
    bool geM05 = rv >= -0.5f;
    bool le0   = rv <=  0.0f;
    bool ge0   = rv >=  0.0f;
    bool le05  = rv <=  0.5f;
    bool ge05  = rv >=  0.5f;
    bool le1   = rv <=  1.0f;
    bool in0 = geM1  && le1;
    bool in1 = geM1  && leM05;
    bool in2 = geM05 && le0;
    bool in3 = ge0   && le05;
    bool in4 = ge05  && le1;
    s[0] += in0 ? d : 0.f;  c[0] += in0 ? 1.f : 0.f;
    s[1] += in1 ? d : 0.f;  c[1] += in1 ? 1.f : 0.f;
    s[2] += in2 ? d : 0.f;  c[2] += in2 ? 1.f : 0.f;
    s[3] += in3 ? d : 0.f;  c[3] += in3 ? 1.f : 0.f;
    s[4] += in4 ? d : 0.f;  c[4] += in4 ? 1.f : 0.f;
    // class value directly as float: -1, -.5, 0, .5, 1 (last matching wins)
    ov = in4 ? 1.0f : (in3 ? 0.5f : (in2 ? 0.0f : (in1 ? -0.5f : -1.0f)));
}

__device__ __forceinline__ void proc_group(int i, const float4& p, const float4& r,
                                           float s[5], float c[5],
                                           float* __restrict__ mask_out)
{
    float ov0, ov1, ov2, ov3;
    proc_elem(p.x, r.x, s, c, ov0);
    proc_elem(p.y, r.y, s, c, ov1);
    proc_elem(p.z, r.z, s, c, ov2);
    proc_elem(p.w, r.w, s, c, ov3);
    // mask_out = d_out+6: 8-byte aligned only -> float2 stores.
    // nontemporal: mask is never re-read; keep L2/L3 for the inputs.
    nfloat2* mo = (nfloat2*)(mask_out + 4 * (size_t)i);
    nfloat2 a; a.x = ov0; a.y = ov1;
    nfloat2 b; b.x = ov2; b.y = ov3;
    __builtin_nontemporal_store(a, mo);
    __builtin_nontemporal_store(b, mo + 1);
}

__global__ __launch_bounds__(TPB, 8) void mcl_main(
    const float* __restrict__ pre, const float* __restrict__ real,
    float* __restrict__ mask_out, float* __restrict__ acc, int n4, int n)
{
    float s[5] = {0.f, 0.f, 0.f, 0.f, 0.f};
    float c[5] = {0.f, 0.f, 0.f, 0.f, 0.f};

    const int t = threadIdx.x;
    const int base = blockIdx.x * SPAN + t;

    const float4* pre4  = (const float4*)pre;
    const float4* real4 = (const float4*)real;

    // 8 float4-pairs per thread in 4 batches of 2; full unroll lets the
    // compiler hoist the next batch's loads over the current batch's compute
    // (pipelined issue instead of one lockstep burst).
#pragma unroll
    for (int k = 0; k < GROUPS; k += 2) {
        int i0 = base + k * TPB;
        int i1 = i0 + TPB;
        bool v0 = i0 < n4;
        bool v1 = i1 < n4;
        float4 p0, r0, p1, r1;
        if (v0) { p0 = pre4[i0]; r0 = real4[i0]; }
        if (v1) { p1 = pre4[i1]; r1 = real4[i1]; }
        if (v0) proc_group(i0, p0, r0, s, c, mask_out);
        if (v1) proc_group(i1, p1, r1, s, c, mask_out);
    }

    // scalar tail (n not divisible by 4)
    {
        int tail_base = n4 * 4;
        int tail = n - tail_base;
        int gtid = blockIdx.x * TPB + t;
        if (gtid < tail) {
            int idx = tail_base + gtid;
            float ov;
            proc_elem(pre[idx], real[idx], s, c, ov);
            mask_out[idx] = ov;
        }
    }

    // wave64 butterfly reduction (10 floats)
#pragma unroll
    for (int j = 0; j < 5; ++j) {
#pragma unroll
        for (int off = 32; off > 0; off >>= 1) {
            s[j] += __shfl_down(s[j], off, 64);
            c[j] += __shfl_down(c[j], off, 64);
        }
    }

    __shared__ float ls[4][5];
    __shared__ float lc[4][5];
    int lane = t & 63;
    int wave = t >> 6;
    if (lane == 0) {
#pragma unroll
        for (int j = 0; j < 5; ++j) { ls[wave][j] = s[j]; lc[wave][j] = c[j]; }
    }
    __syncthreads();
    // 10 lanes, one atomic each; 2048 blocks over 256 banks -> chain depth 8
    if (t < 10) {
        int j = (t < 5) ? t : t - 5;
        float v = (t < 5) ? (ls[0][j] + ls[1][j] + ls[2][j] + ls[3][j])
                          : (lc[0][j] + lc[1][j] + lc[2][j] + lc[3][j]);
        float* bank = acc + (size_t)(blockIdx.x & (N_BANKS - 1)) * BANK_F;
        atomicAdd(&bank[t], v);   // sums at [0..4], counts at [5..9]
    }
}

__global__ void mcl_final(const float* __restrict__ acc, float* __restrict__ out)
{
    // one wave: lane l serially sums banks l, l+64, l+128, l+192, then butterfly
    int l = threadIdx.x;
    float sum[10];
#pragma unroll
    for (int j = 0; j < 10; ++j) sum[j] = 0.f;
#pragma unroll
    for (int b = 0; b < N_BANKS / 64; ++b) {
        const float* bank = acc + (size_t)(b * 64 + l) * BANK_F;
#pragma unroll
        for (int j = 0; j < 10; ++j) sum[j] += bank[j];
    }
#pragma unroll
    for (int j = 0; j < 10; ++j) {
#pragma unroll
        for (int off = 32; off > 0; off >>= 1) {
            sum[j] += __shfl_down(sum[j], off, 64);
        }
    }
    if (l == 0) {
        float total = 0.f;
#pragma unroll
        for (int j = 0; j < 5; ++j) {
            float cnt = sum[5 + j];                 // exact integer-valued float
            float denom = cnt > 1.f ? cnt : 1.f;    // max(count, 1)
            float lv = (cnt == 0.f) ? 0.f : (sum[j] / denom) * 0.2f;
            out[1 + j] = lv;
            total += lv;
        }
        out[0] = total;
    }
}

extern "C" void kernel_launch(void* const* d_in, const int* in_sizes, int n_in,
                              void* d_out, int out_size, void* d_ws, size_t ws_size,
                              hipStream_t stream) {
    const float* pre  = (const float*)d_in[0];
    const float* real = (const float*)d_in[1];
    float* out = (float*)d_out;
    int n = in_sizes[0];
    int n4 = n / 4;

    float* acc = (float*)d_ws;  // 256 banks x 16 floats = 16 KB

    // d_ws re-poisoned to 0xAA before every timed call — zero each launch.
    (void)hipMemsetAsync(d_ws, 0, N_BANKS * BANK_F * sizeof(float), stream);

    int blocks = (n4 + SPAN - 1) / SPAN;            // 2048 for N=16M
    if (blocks < 1) blocks = 1;
    mcl_main<<<blocks, TPB, 0, stream>>>(pre, real, out + 6, acc, n4, n);
    mcl_final<<<1, 64, 0, stream>>>(acc, out);
}